// Round 5
// baseline (68569.427 us; speedup 1.0000x reference)
//
#include <hip/hip_runtime.h>
#include <math.h>

#define SEQ 8192
#define IN_DIM 128
#define HID 512
#define OUT_DIM 128
#define NK 9      // 8 spline basis + 1 silu slot
#define KNOTS 12

// ws layout (floats). W9HU region is reused for W9O by build2 (after seq).
#define WS_W9HU  0                               // 128*9*512 = 589,824 (xpart W); later W9O (512*9*128, same size)
#define WS_WSP   589824                          // 512*64*64 = 2,097,152 (seq spline w: [o][lane][ci][k])
#define WS_WSL   (WS_WSP + 2097152)              // 512*64*8  = 262,144  (seq silu w: [o][lane][ci])
#define WS_XPART (WS_WSL + 262144)               // 8192*512
#define WS_HCOMM (WS_XPART + 4194304)            // 8192*512
#define WS_TOTAL (WS_HCOMM + 4194304)            // 45.4 MB

#define SENTINEL 0x7FA0DEADu   // sNaN payload; never produced by arithmetic

#define TPB2 64                // one wave per block
#define NWG2 512               // one block per output

// 8-way register mux, constant-index accesses only (stays in VGPRs)
__device__ __forceinline__ float sel8(float a0,float a1,float a2,float a3,
                                      float a4,float a5,float a6,float a7,int k){
    float lo = (k&2) ? ((k&1)?a3:a2) : ((k&1)?a1:a0);
    float hi = (k&2) ? ((k&1)?a7:a6) : ((k&1)?a5:a4);
    return (k&4) ? hi : lo;
}

// closed-form uniform cubic B-spline row (for LDS-table kernels: xpart/outlayer)
__device__ __forceinline__ int rowoff(int r) { return r*12 + ((r>>3)<<2); } // 16B skew per 8 rows
__device__ __forceinline__ void write_basis_row(float x, float g0, float inv_h,
                                                float* basf, int row) {
    float* rowp = basf + rowoff(row);
    float tq = (x - g0) * inv_h;
    float cf = floorf(tq);
    float u  = tq - cf;
    int   c  = (int)cf;
    float si = x * __builtin_amdgcn_rcpf(1.0f + __expf(-x));
    ((float4*)rowp)[0] = make_float4(0.f, 0.f, 0.f, 0.f);
    ((float4*)rowp)[1] = make_float4(0.f, 0.f, 0.f, 0.f);
    ((float4*)rowp)[2] = make_float4(si, 0.f, 0.f, 0.f);
    if (c >= 0 && c <= 10) {
        float um = 1.0f - u;
        float u2 = u*u, u3 = u2*u;
        float w0 = um*um*um*(1.0f/6.0f);
        float w1 = 0.5f*u3 - u2 + (2.0f/3.0f);
        float w2 = -0.5f*u3 + 0.5f*u2 + 0.5f*u + (1.0f/6.0f);
        float w3 = u3*(1.0f/6.0f);
        int j0 = c - 3;
        if (j0     >= 0)              rowp[j0]     = w0;
        if (j0 + 1 >= 0 && j0+1 <= 7) rowp[j0 + 1] = w1;
        if (j0 + 2 >= 0 && j0+2 <= 7) rowp[j0 + 2] = w2;
        if (j0 + 3 <= 7)              rowp[j0 + 3] = w3;
    }
}

// ---------------- build1: xpart weights + seq weights + sentinel fill ----------------
__global__ __launch_bounds__(256) void build1_kernel(
    const float* __restrict__ hu_coef, const float* __restrict__ hu_sb, const float* __restrict__ hu_ssp,
    float* __restrict__ ws)
{
    int idx = blockIdx.x * blockDim.x + threadIdx.x;
    int stride = gridDim.x * blockDim.x;
    // xpart slab: [i<128][k<9][o<512]
    const int N1 = 128 * 9 * 512;
    for (int p = idx; p < N1; p += stride) {
        int o = p & 511; int k = (p >> 9) % 9; int i = p / 4608;
        float v = (k < 8) ? hu_ssp[i*HID + o] * hu_coef[(i*HID + o)*8 + k] : hu_sb[i*HID + o];
        ws[WS_W9HU + p] = v;
    }
    // seq spline slab: [o<512][l<64][ci<8][k<8], h-input i = 8*l + ci, global gi = 128 + i
    const int N2 = 512 * 64 * 64;
    for (int q = idx; q < N2; q += stride) {
        int k = q & 7; int ci = (q >> 3) & 7; int l = (q >> 6) & 63; int o = q >> 12;
        int gi = IN_DIM + 8*l + ci;
        ws[WS_WSP + q] = hu_ssp[gi*HID + o] * hu_coef[(gi*HID + o)*8 + k];
    }
    // seq silu slab: [o<512][l<64][ci<8]
    const int N3 = 512 * 64 * 8;
    for (int r = idx; r < N3; r += stride) {
        int ci = r & 7; int l = (r >> 3) & 63; int o = r >> 9;
        int gi = IN_DIM + 8*l + ci;
        ws[WS_WSL + r] = hu_sb[gi*HID + o];
    }
    // sentinel fill
    unsigned* hc = (unsigned*)(ws + WS_HCOMM);
    for (int p = idx; p < SEQ*HID; p += stride) hc[p] = SENTINEL;
}

// ---------------- build2: output-layer weights (overlays W9HU; runs after seq) ----------------
__global__ __launch_bounds__(256) void build2_kernel(
    const float* __restrict__ out_coef, const float* __restrict__ out_sb, const float* __restrict__ out_ssp,
    float* __restrict__ ws)
{
    int idx = blockIdx.x * blockDim.x + threadIdx.x;
    int stride = gridDim.x * blockDim.x;
    const int N = 512 * 9 * 128;   // [i<512][k<9][o<128]
    for (int p = idx; p < N; p += stride) {
        int o = p & 127; int k = (p >> 7) % 9; int i = p / 1152;
        float v = (k < 8) ? out_ssp[i*OUT_DIM + o] * out_coef[(i*OUT_DIM + o)*8 + k] : out_sb[i*OUT_DIM + o];
        ws[WS_W9HU + p] = v;
    }
}

// ---------------- phase 1: x-part contributions (parallel) ----------------
#define R1 4
__global__ __launch_bounds__(256) void xpart_kernel(
    const float* __restrict__ X, const float* __restrict__ hu_grid, float* __restrict__ ws)
{
    const int tid = threadIdx.x;
    const int t0 = blockIdx.x * R1;
    const float* W9 = ws + WS_W9HU;
    float* xpart = ws + WS_XPART;
    float g0 = hu_grid[0];
    float inv_h = 1.0f / (hu_grid[1] - hu_grid[0]);

    __shared__ float basf[R1*IN_DIM*12 + ((R1*IN_DIM)/8)*4];
    #pragma unroll
    for (int rep = 0; rep < 2; ++rep) {
        int idx = tid + rep*256;
        int r = idx >> 7, i = idx & 127;
        write_basis_row(X[(t0 + r)*IN_DIM + i], g0, inv_h, basf, idx);
    }
    __syncthreads();

    float acc[R1][2];
    #pragma unroll
    for (int r = 0; r < R1; ++r) { acc[r][0] = 0.f; acc[r][1] = 0.f; }

    for (int i = 0; i < IN_DIM; ++i) {
        float w1[9], w2[9];
        #pragma unroll
        for (int k = 0; k < 9; ++k) {
            w1[k] = W9[(i*NK+k)*HID + tid];
            w2[k] = W9[(i*NK+k)*HID + tid + 256];
        }
        #pragma unroll
        for (int r = 0; r < R1; ++r) {
            const float* rp = basf + rowoff(r*IN_DIM + i);
            float4 b0 = ((const float4*)rp)[0], b1 = ((const float4*)rp)[1];
            float b8 = rp[8];
            float s1 = w1[0]*b0.x + w1[1]*b0.y + w1[2]*b0.z + w1[3]*b0.w
                     + w1[4]*b1.x + w1[5]*b1.y + w1[6]*b1.z + w1[7]*b1.w + w1[8]*b8;
            float s2 = w2[0]*b0.x + w2[1]*b0.y + w2[2]*b0.z + w2[3]*b0.w
                     + w2[4]*b1.x + w2[5]*b1.y + w2[6]*b1.z + w2[7]*b1.w + w2[8]*b8;
            acc[r][0] += s1; acc[r][1] += s2;
        }
    }
    #pragma unroll
    for (int r = 0; r < R1; ++r) {
        xpart[(t0+r)*HID + tid]       = acc[r][0];
        xpart[(t0+r)*HID + tid + 256] = acc[r][1];
    }
}

// ---------------- phase 2: sequential recurrence (wave-per-output, lane-private, no LDS) ----------------
__global__ __launch_bounds__(TPB2) void seq_kernel(
    const float* __restrict__ h0, const float* __restrict__ hu_grid,
    float* __restrict__ ws, float* __restrict__ d_out)
{
    const int lane = threadIdx.x;               // 0..63
    const int o    = blockIdx.x;                // this wave's output
    const float* WSP = ws + WS_WSP;
    const float* WSL = ws + WS_WSL;
    const float* xpart = ws + WS_XPART;
    float* hcomm = ws + WS_HCOMM;
    float* hs_out = d_out + (size_t)SEQ*OUT_DIM;
    const float g0 = hu_grid[0];
    const float inv_h = 1.0f / (hu_grid[1] - hu_grid[0]);

    // register-resident weights: lane covers h-inputs i = 8*lane + ci
    float w[8][8], wsl[8];
    {
        const float4* wp4 = (const float4*)(WSP + ((size_t)o*64 + lane)*64);
        #pragma unroll
        for (int ci = 0; ci < 8; ++ci) {
            float4 A = wp4[ci*2], B = wp4[ci*2+1];
            w[ci][0]=A.x; w[ci][1]=A.y; w[ci][2]=A.z; w[ci][3]=A.w;
            w[ci][4]=B.x; w[ci][5]=B.y; w[ci][6]=B.z; w[ci][7]=B.w;
        }
        const float4* ws4 = (const float4*)(WSL + ((size_t)o*64 + lane)*8);
        float4 S0 = ws4[0], S1 = ws4[1];
        wsl[0]=S0.x; wsl[1]=S0.y; wsl[2]=S0.z; wsl[3]=S0.w;
        wsl[4]=S1.x; wsl[5]=S1.y; wsl[6]=S1.z; wsl[7]=S1.w;
    }

    for (int t = 0; t < SEQ; ++t) {
        float xf = xpart[t*HID + o];            // broadcast line, poll-independent

        float hv[8];
        if (t == 0) {
            #pragma unroll
            for (int ci = 0; ci < 8; ++ci) hv[ci] = h0[8*lane + ci];
        } else {
            const unsigned* row = (const unsigned*)&hcomm[(size_t)(t-1)*HID + 8*lane];
            unsigned v[8];
            for (;;) {
                bool all_ok = true;
                #pragma unroll
                for (int ci = 0; ci < 8; ++ci) {
                    v[ci] = __hip_atomic_load(row + ci, __ATOMIC_RELAXED, __HIP_MEMORY_SCOPE_AGENT);
                }
                #pragma unroll
                for (int ci = 0; ci < 8; ++ci) all_ok = all_ok && (v[ci] != SENTINEL);
                if (all_ok) break;
            }
            #pragma unroll
            for (int ci = 0; ci < 8; ++ci) hv[ci] = __uint_as_float(v[ci]);
        }

        float a0 = 0.f, a1 = 0.f;
        #pragma unroll
        for (int ci = 0; ci < 8; ++ci) {
            float x = hv[ci];
            float tq = (x - g0) * inv_h;
            float cf = floorf(tq);
            float u  = tq - cf;
            int   c  = (int)cf;
            float um = 1.0f - u;
            float u2 = u*u, u3 = u2*u;
            float P0 = um*um*um*(1.0f/6.0f);
            float P1 = 0.5f*u3 - u2 + (2.0f/3.0f);
            float P2 = -0.5f*u3 + 0.5f*u2 + 0.5f*u + (1.0f/6.0f);
            float P3 = u3*(1.0f/6.0f);
            int b = c - 3;
            float sp = 0.f;
            {   int k = b;     float t0s = sel8(w[ci][0],w[ci][1],w[ci][2],w[ci][3],w[ci][4],w[ci][5],w[ci][6],w[ci][7], k&7);
                sp += (((unsigned)k) < 8u ? P0 : 0.f) * t0s; }
            {   int k = b + 1; float t1s = sel8(w[ci][0],w[ci][1],w[ci][2],w[ci][3],w[ci][4],w[ci][5],w[ci][6],w[ci][7], k&7);
                sp += (((unsigned)k) < 8u ? P1 : 0.f) * t1s; }
            {   int k = b + 2; float t2s = sel8(w[ci][0],w[ci][1],w[ci][2],w[ci][3],w[ci][4],w[ci][5],w[ci][6],w[ci][7], k&7);
                sp += (((unsigned)k) < 8u ? P2 : 0.f) * t2s; }
            {   int k = b + 3; float t3s = sel8(w[ci][0],w[ci][1],w[ci][2],w[ci][3],w[ci][4],w[ci][5],w[ci][6],w[ci][7], k&7);
                sp += (((unsigned)k) < 8u ? P3 : 0.f) * t3s; }
            float si = x * __builtin_amdgcn_rcpf(1.0f + __expf(-x));
            if (ci & 1) a1 += sp + wsl[ci]*si;
            else        a0 += sp + wsl[ci]*si;
        }
        float acc = a0 + a1;
        acc += __shfl_xor(acc, 1, 64);
        acc += __shfl_xor(acc, 2, 64);
        acc += __shfl_xor(acc, 4, 64);
        acc += __shfl_xor(acc, 8, 64);
        acc += __shfl_xor(acc, 16, 64);
        acc += __shfl_xor(acc, 32, 64);
        if (lane == 0) {
            float s = acc + xf;
            __hip_atomic_store((unsigned*)&hcomm[(size_t)t*HID + o], __float_as_uint(s),
                               __ATOMIC_RELAXED, __HIP_MEMORY_SCOPE_AGENT);
            hs_out[(size_t)t*HID + o] = s;
        }
    }
}

// ---------------- phase 3: output layer (parallel) ----------------
#define R3 2
__global__ __launch_bounds__(256) void outlayer_kernel(
    const float* __restrict__ out_grid, float* __restrict__ ws, float* __restrict__ d_out)
{
    const int tid = threadIdx.x;
    const int t0 = blockIdx.x * R3;
    const float* W9o = ws + WS_W9HU;   // overlaid by build2
    const float* hs = d_out + (size_t)SEQ*OUT_DIM;
    float g0 = out_grid[0];
    float inv_h = 1.0f / (out_grid[1] - out_grid[0]);

    __shared__ float basf[R3*HID*12 + ((R3*HID)/8)*4];
    #pragma unroll
    for (int rep = 0; rep < 4; ++rep) {
        int idx = tid + rep*256;
        int r = idx >> 9, i = idx & 511;
        write_basis_row(hs[(size_t)(t0+r)*HID + i], g0, inv_h, basf, idx);
    }
    __syncthreads();

    const int oo = tid & 127;
    const int half = tid >> 7;
    float acc[R3] = {0.f, 0.f};
    for (int ii = 0; ii < 256; ++ii) {
        int i = half*256 + ii;
        float wv[9];
        #pragma unroll
        for (int k = 0; k < 9; ++k) wv[k] = W9o[(i*NK+k)*OUT_DIM + oo];
        #pragma unroll
        for (int r = 0; r < R3; ++r) {
            const float* rp = basf + rowoff(r*HID + i);
            float4 b0 = ((const float4*)rp)[0], b1 = ((const float4*)rp)[1];
            float b8 = rp[8];
            acc[r] += wv[0]*b0.x + wv[1]*b0.y + wv[2]*b0.z + wv[3]*b0.w
                    + wv[4]*b1.x + wv[5]*b1.y + wv[6]*b1.z + wv[7]*b1.w + wv[8]*b8;
        }
    }
    __shared__ float red[2][R3][128];
    red[half][0][oo] = acc[0];
    red[half][1][oo] = acc[1];
    __syncthreads();
    {
        int rr = tid >> 7, o2 = tid & 127;
        d_out[(size_t)(t0+rr)*OUT_DIM + o2] = red[0][rr][o2] + red[1][rr][o2];
    }
}

extern "C" void kernel_launch(void* const* d_in, const int* in_sizes, int n_in,
                              void* d_out, int out_size, void* d_ws, size_t ws_size,
                              hipStream_t stream) {
    (void)in_sizes; (void)n_in; (void)out_size; (void)ws_size;
    const float* X        = (const float*)d_in[0];
    const float* h0       = (const float*)d_in[1];
    const float* hu_grid  = (const float*)d_in[2];
    const float* hu_coef  = (const float*)d_in[3];
    const float* hu_sb    = (const float*)d_in[4];
    const float* hu_ssp   = (const float*)d_in[5];
    const float* out_grid = (const float*)d_in[6];
    const float* out_coef = (const float*)d_in[7];
    const float* out_sb   = (const float*)d_in[8];
    const float* out_ssp  = (const float*)d_in[9];
    float* out = (float*)d_out;
    float* ws  = (float*)d_ws;

    hipLaunchKernelGGL(build1_kernel, dim3(2048), dim3(256), 0, stream,
                       hu_coef, hu_sb, hu_ssp, ws);
    hipLaunchKernelGGL(xpart_kernel, dim3(SEQ/R1), dim3(256), 0, stream, X, hu_grid, ws);
    hipLaunchKernelGGL(seq_kernel, dim3(NWG2), dim3(TPB2), 0, stream, h0, hu_grid, ws, out);
    hipLaunchKernelGGL(build2_kernel, dim3(1024), dim3(256), 0, stream,
                       out_coef, out_sb, out_ssp, ws);
    hipLaunchKernelGGL(outlayer_kernel, dim3(SEQ/R3), dim3(256), 0, stream, out_grid, ws, out);
}

// Round 6
// 16789.888 us; speedup vs baseline: 4.0840x; 4.0840x over previous
//
#include <hip/hip_runtime.h>
#include <math.h>

#define SEQ 8192
#define IN_DIM 128
#define HID 512
#define OUT_DIM 128
#define NK 9      // 8 spline basis + 1 silu slot
#define KNOTS 12

// ws layout (floats). W9HU region reused for W9O by build2 (after seq).
#define WS_W9HU  0                           // 128*9*512 = 589,824 (xpart W); later W9O (512*9*128, same size)
#define WS_WSEQ  589824                      // 32*128*4*4*4*9 = 2,359,296 (seq W: [blk][q][oq][r][j][k])
#define WS_XPART (WS_WSEQ + 2359296)         // 8192*512
#define WS_HCOMM (WS_XPART + 4194304)        // 8192*512
#define WS_TOTAL (WS_HCOMM + 4194304)        // 11,337,728 floats = 45.4 MB

#define SENTINEL 0x7FA0DEADu   // sNaN payload; never produced by arithmetic

#define NWG 32
#define TPB2 512

__device__ __forceinline__ int brow(int ib) { return ib*3 + (ib >> 4); } // float4 row idx, bank-skew (R2-proven)

__device__ __forceinline__ void load_knots(const float* gptr, float* g, float* invA) {
    #pragma unroll
    for (int j = 0; j < KNOTS; ++j) g[j] = gptr[j];
    #pragma unroll
    for (int d = 1; d <= 3; ++d) {
        #pragma unroll
        for (int j = 0; j < 11; ++j) {
            if (j + d <= 11) invA[(d-1)*11 + j] = 1.0f / (g[j+d] - g[j]);
        }
    }
}

// Exact Cox-de Boor (degree 3) + silu — used by parallel kernels (R2-proven)
__device__ __forceinline__ void basis9(float x, const float* g, const float* invA, float* out) {
    float B[11];
    #pragma unroll
    for (int j = 0; j < 11; ++j)
        B[j] = (x >= g[j] && x < g[j+1]) ? 1.0f : 0.0f;
    #pragma unroll
    for (int d = 1; d <= 3; ++d) {
        #pragma unroll
        for (int j = 0; j < 11; ++j) {
            if (j + d < 11) {
                float left  = (x - g[j]) * invA[(d-1)*11 + j];
                float right = (g[j+d+1] - x) * invA[(d-1)*11 + j + 1];
                B[j] = left * B[j] + right * B[j+1];
            }
        }
    }
    #pragma unroll
    for (int j = 0; j < 8; ++j) out[j] = B[j];
    out[8] = x / (1.0f + expf(-x));  // silu
}

// ---------------- build1: xpart weights + seq weights + sentinel fill ----------------
__global__ __launch_bounds__(256) void build1_kernel(
    const float* __restrict__ hu_coef, const float* __restrict__ hu_sb, const float* __restrict__ hu_ssp,
    float* __restrict__ ws)
{
    int idx = blockIdx.x * blockDim.x + threadIdx.x;
    int stride = gridDim.x * blockDim.x;
    // xpart slab: [i<128][k<9][o<512]
    const int N1 = 128 * 9 * 512;
    for (int p = idx; p < N1; p += stride) {
        int o = p & 511; int k = (p >> 9) % 9; int i = p / 4608;
        float v = (k < 8) ? hu_ssp[i*HID + o] * hu_coef[(i*HID + o)*8 + k] : hu_sb[i*HID + o];
        ws[WS_W9HU + p] = v;
    }
    // seq slab: [blk<32][q<128][oq<4][r<4][j<4][k<9]; input gi=128+4q+r, output o=blk*16+oq*4+j
    const int N2 = 32 * 128 * 4 * 4 * 4 * 9;
    for (int p = idx; p < N2; p += stride) {
        int k = p % 9; int rest = p / 9;
        int j = rest & 3; rest >>= 2;
        int r = rest & 3; rest >>= 2;
        int oq = rest & 3; rest >>= 2;
        int q = rest & 127; int blk = rest >> 7;
        int gi = IN_DIM + 4*q + r;
        int o  = blk*16 + oq*4 + j;
        float v = (k < 8) ? hu_ssp[gi*HID + o] * hu_coef[(gi*HID + o)*8 + k] : hu_sb[gi*HID + o];
        ws[WS_WSEQ + p] = v;
    }
    // sentinel fill
    unsigned* hc = (unsigned*)(ws + WS_HCOMM);
    for (int p = idx; p < SEQ*HID; p += stride) hc[p] = SENTINEL;
}

// ---------------- build2: output-layer weights (overlays W9HU; runs after seq) ----------------
__global__ __launch_bounds__(256) void build2_kernel(
    const float* __restrict__ out_coef, const float* __restrict__ out_sb, const float* __restrict__ out_ssp,
    float* __restrict__ ws)
{
    int idx = blockIdx.x * blockDim.x + threadIdx.x;
    int stride = gridDim.x * blockDim.x;
    const int N = 512 * 9 * 128;   // [i<512][k<9][o<128]
    for (int p = idx; p < N; p += stride) {
        int o = p & 127; int k = (p >> 7) % 9; int i = p / 1152;
        float v = (k < 8) ? out_ssp[i*OUT_DIM + o] * out_coef[(i*OUT_DIM + o)*8 + k] : out_sb[i*OUT_DIM + o];
        ws[WS_W9HU + p] = v;
    }
}

// ---------------- phase 1: x-part contributions (R2-proven form) ----------------
#define R1 4
__global__ __launch_bounds__(256) void xpart_kernel(
    const float* __restrict__ X, const float* __restrict__ hu_grid, float* __restrict__ ws)
{
    const int tid = threadIdx.x;
    const int t0 = blockIdx.x * R1;
    const float* W9 = ws + WS_W9HU;
    float* xpart = ws + WS_XPART;
    float g[KNOTS], invA[33];
    load_knots(hu_grid, g, invA);

    __shared__ float4 bas4[R1*IN_DIM*3 + (R1*IN_DIM)/16];
    #pragma unroll
    for (int rep = 0; rep < 2; ++rep) {
        int idx = tid + rep*256;
        int r = idx >> 7, i = idx & 127;
        float bv[9];
        basis9(X[(t0 + r)*IN_DIM + i], g, invA, bv);
        int rb = brow(idx);
        bas4[rb]   = make_float4(bv[0], bv[1], bv[2], bv[3]);
        bas4[rb+1] = make_float4(bv[4], bv[5], bv[6], bv[7]);
        bas4[rb+2] = make_float4(bv[8], 0.f, 0.f, 0.f);
    }
    __syncthreads();

    float acc[R1][2];
    #pragma unroll
    for (int r = 0; r < R1; ++r) { acc[r][0] = 0.f; acc[r][1] = 0.f; }

    for (int i = 0; i < IN_DIM; ++i) {
        float w1[9], w2[9];
        #pragma unroll
        for (int k = 0; k < 9; ++k) {
            w1[k] = W9[(i*NK+k)*HID + tid];
            w2[k] = W9[(i*NK+k)*HID + tid + 256];
        }
        #pragma unroll
        for (int r = 0; r < R1; ++r) {
            const float* rp = (const float*)&bas4[brow(r*IN_DIM + i)];
            float4 b0 = ((const float4*)rp)[0], b1 = ((const float4*)rp)[1];
            float b8 = rp[8];
            float s1 = w1[0]*b0.x + w1[1]*b0.y + w1[2]*b0.z + w1[3]*b0.w
                     + w1[4]*b1.x + w1[5]*b1.y + w1[6]*b1.z + w1[7]*b1.w + w1[8]*b8;
            float s2 = w2[0]*b0.x + w2[1]*b0.y + w2[2]*b0.z + w2[3]*b0.w
                     + w2[4]*b1.x + w2[5]*b1.y + w2[6]*b1.z + w2[7]*b1.w + w2[8]*b8;
            acc[r][0] += s1; acc[r][1] += s2;
        }
    }
    #pragma unroll
    for (int r = 0; r < R1; ++r) {
        xpart[(t0+r)*HID + tid]       = acc[r][0];
        xpart[(t0+r)*HID + tid + 256] = acc[r][1];
    }
}

// ---------------- phase 2: sequential recurrence (R2 poll/publish + reg-resident W + closed-form basis) ----------------
__global__ __launch_bounds__(TPB2, 2) void seq_kernel(
    const float* __restrict__ h0, const float* __restrict__ hu_grid,
    float* __restrict__ ws, float* __restrict__ d_out)
{
    const int tid  = threadIdx.x;
    const int blk  = blockIdx.x;
    const int lane = tid & 63;
    const int wave = tid >> 6;
    const int oq   = tid & 3;        // output quad (broadcast-friendly: 4 lanes share rows)
    const int q    = tid >> 2;       // input quad 0..127
    const float* xpart = ws + WS_XPART;
    float* hcomm = ws + WS_HCOMM;
    float* hs_out = d_out + (size_t)SEQ*OUT_DIM;
    const float g0 = hu_grid[0];
    const float inv_h = 1.0f / (hu_grid[1] - hu_grid[0]);

    // register-resident weights: inputs 4q+r (r<4), outputs blk*16+oq*4+j (j<4)
    float w[4][4][9];
    {
        const float* Wb = ws + WS_WSEQ + ((size_t)((blk*128 + q)*4 + oq))*144;
        #pragma unroll
        for (int r = 0; r < 4; ++r)
            #pragma unroll
            for (int j = 0; j < 4; ++j)
                #pragma unroll
                for (int k = 0; k < 9; ++k)
                    w[r][j][k] = Wb[(r*4 + j)*9 + k];
    }

    __shared__ float4 bas4[3*HID + HID/16 + 4];
    __shared__ float red[8][4][4];

    for (int t = 0; t < SEQ; ++t) {
        float xf = (tid < 16) ? xpart[(size_t)t*HID + blk*16 + tid] : 0.0f;  // poll-independent

        float hv;
        if (t == 0) {
            hv = h0[tid];
        } else {
            const unsigned* pp = (const unsigned*)&hcomm[(size_t)(t-1)*HID + tid];
            unsigned u = __hip_atomic_load(pp, __ATOMIC_RELAXED, __HIP_MEMORY_SCOPE_AGENT);
            int sp = 0;
            while (u == SENTINEL && ++sp < (1 << 24))
                u = __hip_atomic_load(pp, __ATOMIC_RELAXED, __HIP_MEMORY_SCOPE_AGENT);
            hv = __uint_as_float(u);
        }

        // closed-form uniform cubic basis -> LDS row tid
        {
            float* rowp = (float*)&bas4[brow(tid)];
            float tq = (hv - g0) * inv_h;
            float cf = floorf(tq);
            float u  = tq - cf;
            int   c  = (int)cf;
            float si = hv * __builtin_amdgcn_rcpf(1.0f + __expf(-hv));
            ((float4*)rowp)[0] = make_float4(0.f, 0.f, 0.f, 0.f);
            ((float4*)rowp)[1] = make_float4(0.f, 0.f, 0.f, 0.f);
            rowp[8] = si;
            if (c >= 0 && c <= 10) {
                float um = 1.0f - u, u2 = u*u, u3 = u2*u;
                float P0 = um*um*um*(1.0f/6.0f);
                float P1 = 0.5f*u3 - u2 + (2.0f/3.0f);
                float P2 = -0.5f*u3 + 0.5f*u2 + 0.5f*u + (1.0f/6.0f);
                float P3 = u3*(1.0f/6.0f);
                int j0 = c - 3;
                if (j0     >= 0)              rowp[j0]     = P0;
                if (j0 + 1 >= 0 && j0+1 <= 7) rowp[j0 + 1] = P1;
                if (j0 + 2 >= 0 && j0+2 <= 7) rowp[j0 + 2] = P2;
                if (j0 + 3 <= 7)              rowp[j0 + 3] = P3;
            }
        }
        __syncthreads();

        float p0 = 0.f, p1 = 0.f, p2 = 0.f, p3 = 0.f;
        #pragma unroll
        for (int r = 0; r < 4; ++r) {
            int row = 4*q + r;
            const float* rp = (const float*)&bas4[brow(row)];
            float4 b0 = ((const float4*)rp)[0], b1 = ((const float4*)rp)[1];
            float b8 = rp[8];
            p0 += w[r][0][0]*b0.x + w[r][0][1]*b0.y + w[r][0][2]*b0.z + w[r][0][3]*b0.w
                + w[r][0][4]*b1.x + w[r][0][5]*b1.y + w[r][0][6]*b1.z + w[r][0][7]*b1.w + w[r][0][8]*b8;
            p1 += w[r][1][0]*b0.x + w[r][1][1]*b0.y + w[r][1][2]*b0.z + w[r][1][3]*b0.w
                + w[r][1][4]*b1.x + w[r][1][5]*b1.y + w[r][1][6]*b1.z + w[r][1][7]*b1.w + w[r][1][8]*b8;
            p2 += w[r][2][0]*b0.x + w[r][2][1]*b0.y + w[r][2][2]*b0.z + w[r][2][3]*b0.w
                + w[r][2][4]*b1.x + w[r][2][5]*b1.y + w[r][2][6]*b1.z + w[r][2][7]*b1.w + w[r][2][8]*b8;
            p3 += w[r][3][0]*b0.x + w[r][3][1]*b0.y + w[r][3][2]*b0.z + w[r][3][3]*b0.w
                + w[r][3][4]*b1.x + w[r][3][5]*b1.y + w[r][3][6]*b1.z + w[r][3][7]*b1.w + w[r][3][8]*b8;
        }
        // butterfly over stride-4 lane classes (low 2 bits = oq preserved)
        #pragma unroll
        for (int d = 4; d < 64; d <<= 1) {
            p0 += __shfl_xor(p0, d, 64);
            p1 += __shfl_xor(p1, d, 64);
            p2 += __shfl_xor(p2, d, 64);
            p3 += __shfl_xor(p3, d, 64);
        }
        if (lane < 4) {
            red[wave][lane][0] = p0;
            red[wave][lane][1] = p1;
            red[wave][lane][2] = p2;
            red[wave][lane][3] = p3;
        }
        __syncthreads();
        if (tid < 16) {
            float s = xf;
            #pragma unroll
            for (int wv = 0; wv < 8; ++wv) s += red[wv][tid>>2][tid&3];
            __hip_atomic_store((unsigned*)&hcomm[(size_t)t*HID + blk*16 + tid], __float_as_uint(s),
                               __ATOMIC_RELAXED, __HIP_MEMORY_SCOPE_AGENT);
            hs_out[(size_t)t*HID + blk*16 + tid] = s;
        }
        __syncthreads();   // WAR: bas4/red rewritten next step
    }
}

// ---------------- phase 3: output layer (R2-proven form) ----------------
#define R3 2
__global__ __launch_bounds__(256) void outlayer_kernel(
    const float* __restrict__ out_grid, float* __restrict__ ws, float* __restrict__ d_out)
{
    const int tid = threadIdx.x;
    const int t0 = blockIdx.x * R3;
    const float* W9o = ws + WS_W9HU;   // overlaid by build2
    const float* hs = d_out + (size_t)SEQ*OUT_DIM;
    float g[KNOTS], invA[33];
    load_knots(out_grid, g, invA);

    __shared__ float4 bas4[R3*HID*3 + (R3*HID)/16];
    #pragma unroll
    for (int rep = 0; rep < 4; ++rep) {
        int idx = tid + rep*256;
        int r = idx >> 9, i = idx & 511;
        float bv[9];
        basis9(hs[(size_t)(t0+r)*HID + i], g, invA, bv);
        int rb = brow(idx);
        bas4[rb]   = make_float4(bv[0], bv[1], bv[2], bv[3]);
        bas4[rb+1] = make_float4(bv[4], bv[5], bv[6], bv[7]);
        bas4[rb+2] = make_float4(bv[8], 0.f, 0.f, 0.f);
    }
    __syncthreads();

    const int oo = tid & 127;
    const int half = tid >> 7;
    float acc[R3] = {0.f, 0.f};
    for (int ii = 0; ii < 256; ++ii) {
        int i = half*256 + ii;
        float wv[9];
        #pragma unroll
        for (int k = 0; k < 9; ++k) wv[k] = W9o[(i*NK+k)*OUT_DIM + oo];
        #pragma unroll
        for (int r = 0; r < R3; ++r) {
            const float* rp = (const float*)&bas4[brow(r*HID + i)];
            float4 b0 = ((const float4*)rp)[0], b1 = ((const float4*)rp)[1];
            float b8 = rp[8];
            acc[r] += wv[0]*b0.x + wv[1]*b0.y + wv[2]*b0.z + wv[3]*b0.w
                    + wv[4]*b1.x + wv[5]*b1.y + wv[6]*b1.z + wv[7]*b1.w + wv[8]*b8;
        }
    }
    __shared__ float red[2][R3][128];
    red[half][0][oo] = acc[0];
    red[half][1][oo] = acc[1];
    __syncthreads();
    {
        int rr = tid >> 7, o2 = tid & 127;
        d_out[(size_t)(t0+rr)*OUT_DIM + o2] = red[0][rr][o2] + red[1][rr][o2];
    }
}

extern "C" void kernel_launch(void* const* d_in, const int* in_sizes, int n_in,
                              void* d_out, int out_size, void* d_ws, size_t ws_size,
                              hipStream_t stream) {
    (void)in_sizes; (void)n_in; (void)out_size; (void)ws_size;
    const float* X        = (const float*)d_in[0];
    const float* h0       = (const float*)d_in[1];
    const float* hu_grid  = (const float*)d_in[2];
    const float* hu_coef  = (const float*)d_in[3];
    const float* hu_sb    = (const float*)d_in[4];
    const float* hu_ssp   = (const float*)d_in[5];
    const float* out_grid = (const float*)d_in[6];
    const float* out_coef = (const float*)d_in[7];
    const float* out_sb   = (const float*)d_in[8];
    const float* out_ssp  = (const float*)d_in[9];
    float* out = (float*)d_out;
    float* ws  = (float*)d_ws;

    hipLaunchKernelGGL(build1_kernel, dim3(2048), dim3(256), 0, stream,
                       hu_coef, hu_sb, hu_ssp, ws);
    hipLaunchKernelGGL(xpart_kernel, dim3(SEQ/R1), dim3(256), 0, stream, X, hu_grid, ws);
    hipLaunchKernelGGL(seq_kernel, dim3(NWG), dim3(TPB2), 0, stream, h0, hu_grid, ws, out);
    hipLaunchKernelGGL(build2_kernel, dim3(1024), dim3(256), 0, stream,
                       out_coef, out_sb, out_ssp, ws);
    hipLaunchKernelGGL(outlayer_kernel, dim3(SEQ/R3), dim3(256), 0, stream, out_grid, ws, out);
}